// Round 2
// baseline (649.913 us; speedup 1.0000x reference)
//
#include <hip/hip_runtime.h>
#include <hip/hip_bf16.h>

#define N_SRC_ 50000
#define N_DST_ 50000
#define INF_   128
#define OUTF_  128
#define NT_    3
#define FAN_   10
#define BM_    64
#define LSTR_  136   // LDS row stride in shorts (272 B) -> bank-uniform ds_read_b128

typedef __attribute__((ext_vector_type(8))) short          bf16x8;
typedef __attribute__((ext_vector_type(4))) float          f32x4;
typedef __attribute__((ext_vector_type(8))) unsigned short us8;

__device__ __forceinline__ unsigned short f2bf(float f) {
  unsigned u = __float_as_uint(f);
  u = u + 0x7FFFu + ((u >> 16) & 1u);   // RNE
  return (unsigned short)(u >> 16);
}
__device__ __forceinline__ float frcp(float x) { return __builtin_amdgcn_rcpf(x); }
__device__ __forceinline__ float sig_(float x) { return frcp(1.f + __expf(-x)); }
__device__ __forceinline__ float tanh_(float x) { return 1.f - 2.f * frcp(1.f + __expf(2.f * x)); }

// ---------------- prep: feature fp32 -> bf16 ----------------
__global__ void prep_feat(const float* __restrict__ f, unsigned short* __restrict__ o, int n4) {
  int i = blockIdx.x * blockDim.x + threadIdx.x;
  if (i < n4) {
    float4 v = ((const float4*)f)[i];
    ushort4 r;
    r.x = f2bf(v.x); r.y = f2bf(v.y); r.z = f2bf(v.z); r.w = f2bf(v.w);
    ((ushort4*)o)[i] = r;
  }
}

// ---------------- prep: weight reorder + concat + bf16 ----------------
// Wcat[t][nr][k], nr = w*64 + ct*16 + j  <->  orig gate col = ct*128 + w*16 + j
// k<128: W_ih[col][k]; k>=128: W_hh[col][k-128]
// W2cat[t][n][k]: k<128: fc_self_w[n][k]; else fc_neigh_w[n][k-128]
// bcat[t][nr] = (b_ih + b_hh)[col]
__global__ void prep_w(const float* __restrict__ W_ih, const float* __restrict__ W_hh,
                       const float* __restrict__ b_ih, const float* __restrict__ b_hh,
                       const float* __restrict__ fcs,  const float* __restrict__ fcn,
                       unsigned short* __restrict__ Wcat, unsigned short* __restrict__ W2cat,
                       float* __restrict__ bcat) {
  int i = blockIdx.x * blockDim.x + threadIdx.x;
  if (i < NT_ * 512 * 256) {
    int t = i / (512 * 256); int rem = i % (512 * 256);
    int nr = rem >> 8; int kk = rem & 255;
    int w = nr >> 6, ct = (nr >> 4) & 3, j = nr & 15;
    int col = ct * 128 + w * 16 + j;
    float v = (kk < 128) ? W_ih[(t * 512 + col) * 128 + kk]
                         : W_hh[(t * 512 + col) * 128 + (kk - 128)];
    Wcat[i] = f2bf(v);
  } else {
    int i2 = i - NT_ * 512 * 256;
    if (i2 < NT_ * 128 * 256) {
      int t = i2 / (128 * 256); int rem = i2 % (128 * 256);
      int n = rem >> 8; int kk = rem & 255;
      float v = (kk < 128) ? fcs[(t * 128 + n) * 128 + kk]
                           : fcn[(t * 128 + n) * 128 + (kk - 128)];
      W2cat[i2] = f2bf(v);
    } else {
      int i3 = i2 - NT_ * 128 * 256;
      if (i3 < NT_ * 512) {
        int t = i3 / 512; int nr = i3 % 512;
        int col = ((nr >> 4) & 3) * 128 + (nr >> 6) * 16 + (nr & 15);
        bcat[i3] = b_ih[t * 512 + col] + b_hh[t * 512 + col];
      }
    }
  }
}

// ---------------- main fused kernel ----------------
__global__ __launch_bounds__(512) void sage_main(
    const unsigned short* __restrict__ feat16, const int* __restrict__ nidx,
    const unsigned short* __restrict__ Wcat, const float* __restrict__ bcat,
    const unsigned short* __restrict__ W2cat,
    const float* __restrict__ sbias, const float* __restrict__ lnw,
    const float* __restrict__ lnb, float* __restrict__ out) {
  const int t  = blockIdx.y;
  const int r0 = blockIdx.x * BM_;
  const int tid = threadIdx.x;
  const int w  = tid >> 6;     // wave 0..7: owns hidden units [16w,16w+16)
  const int l  = tid & 63;
  const int lg = l >> 4;       // k-group
  const int lr = l & 15;       // row-in-tile (A) / col-in-tile (B,D)

  __shared__ __align__(16) unsigned short lds_x[BM_ * LSTR_];
  __shared__ __align__(16) unsigned short lds_h[2][BM_ * LSTR_];
  __shared__ int   lds_idx[BM_ * FAN_];
  __shared__ float lds_ps[BM_ * 8];
  __shared__ float lds_pq[BM_ * 8];
  __shared__ float lds_mu[BM_];
  __shared__ float lds_ri[BM_];

  // neighbor indices for this row block (contiguous in memory).
  // BM_*FAN_ = 640 > 512 threads -> strided loop (round-0 bug: entries 512..639
  // were uninitialized -> wild gather -> memory fault).
  for (int i = tid; i < BM_ * FAN_; i += 512) {
    int row = i / FAN_;
    int v = 0;
    if (r0 + row < N_DST_) v = nidx[(t * N_DST_ + r0) * FAN_ + i];
    lds_idx[i] = v;
  }

  // register-resident LSTM weights: wave w's 64 rows of Wcat (4 gate tiles x 8 k-iters)
  bf16x8 wfrag[4][8];
  {
    const unsigned short* wb = Wcat + (t * 512 + w * 64) * 256;
#pragma unroll
    for (int ct = 0; ct < 4; ++ct)
#pragma unroll
      for (int kk = 0; kk < 8; ++kk)
        wfrag[ct][kk] = *(const bf16x8*)(wb + (ct * 16 + lr) * 256 + kk * 32 + lg * 8);
  }
  float bias_g[4];
#pragma unroll
  for (int ct = 0; ct < 4; ++ct) bias_g[ct] = bcat[t * 512 + w * 64 + ct * 16 + lr];

  float cst[16];   // c-state: unit = w*16+lr, rows rt*16 + lg*4 + j
#pragma unroll
  for (int q = 0; q < 16; ++q) cst[q] = 0.f;

  const int grow = tid >> 4;   // gather: rows grow, grow+32; chunk gch (16B)
  const int gch  = tid & 15;

  __syncthreads();

#pragma unroll 1
  for (int k = 0; k < FAN_; ++k) {
    // gather X_k rows (bf16) into LDS; clamp indices as fault insurance
    int s0 = lds_idx[grow * FAN_ + k];
    int s1 = lds_idx[(grow + 32) * FAN_ + k];
    s0 = min(max(s0, 0), N_SRC_ - 1);
    s1 = min(max(s1, 0), N_SRC_ - 1);
    us8 v0 = *(const us8*)(feat16 + s0 * INF_ + gch * 8);
    us8 v1 = *(const us8*)(feat16 + s1 * INF_ + gch * 8);
    *(us8*)(lds_x + grow * LSTR_ + gch * 8) = v0;
    *(us8*)(lds_x + (grow + 32) * LSTR_ + gch * 8) = v1;
    __syncthreads();

    f32x4 acc[4][4];
#pragma unroll
    for (int rt = 0; rt < 4; ++rt)
#pragma unroll
      for (int ct = 0; ct < 4; ++ct) {
        acc[rt][ct][0] = bias_g[ct]; acc[rt][ct][1] = bias_g[ct];
        acc[rt][ct][2] = bias_g[ct]; acc[rt][ct][3] = bias_g[ct];
      }

    const unsigned short* hb = lds_h[k & 1];
#pragma unroll
    for (int kk = 0; kk < 8; ++kk) {
      if (kk >= 4 && k == 0) continue;   // h==0 at step 0 (uniform branch)
#pragma unroll
      for (int rt = 0; rt < 4; ++rt) {
        const unsigned short* ab = (kk < 4)
            ? (lds_x + (rt * 16 + lr) * LSTR_ + kk * 32 + lg * 8)
            : (hb    + (rt * 16 + lr) * LSTR_ + (kk - 4) * 32 + lg * 8);
        bf16x8 a = *(const bf16x8*)ab;
#pragma unroll
        for (int ct = 0; ct < 4; ++ct)
          acc[rt][ct] = __builtin_amdgcn_mfma_f32_16x16x32_bf16(a, wfrag[ct][kk], acc[rt][ct], 0, 0, 0);
      }
    }

    // gate activations (i,f,g,o = ct 0..3), update c, write h (bf16) to other buffer
    unsigned short* hw = (unsigned short*)lds_h[(k + 1) & 1];
#pragma unroll
    for (int rt = 0; rt < 4; ++rt)
#pragma unroll
      for (int j = 0; j < 4; ++j) {
        float gi = acc[rt][0][j], gf = acc[rt][1][j], gg = acc[rt][2][j], go = acc[rt][3][j];
        float c2 = sig_(gf) * cst[rt * 4 + j] + sig_(gi) * tanh_(gg);
        cst[rt * 4 + j] = c2;
        float h = sig_(go) * tanh_(c2);
        hw[(rt * 16 + lg * 4 + j) * LSTR_ + w * 16 + lr] = f2bf(h);
      }
    __syncthreads();   // protects lds_x overwrite + h visibility for next step
  }

  // ---------- epilogue: rst = feat@fc_self^T + h@fc_neigh^T + bias; LN; ELU ----------
  // final h is in lds_h[0] (step 9 wrote buffer (9+1)&1 = 0)
  {
    int rw0 = r0 + grow, rw1 = r0 + grow + 32;
    us8 z = {0, 0, 0, 0, 0, 0, 0, 0};
    us8 v0 = (rw0 < N_DST_) ? *(const us8*)(feat16 + rw0 * INF_ + gch * 8) : z;
    us8 v1 = (rw1 < N_DST_) ? *(const us8*)(feat16 + rw1 * INF_ + gch * 8) : z;
    *(us8*)(lds_x + grow * LSTR_ + gch * 8) = v0;
    *(us8*)(lds_x + (grow + 32) * LSTR_ + gch * 8) = v1;
  }
  bf16x8 w2f[8];
  {
    const unsigned short* w2b = W2cat + (t * 128 + w * 16) * 256;
#pragma unroll
    for (int kk = 0; kk < 8; ++kk)
      w2f[kk] = *(const bf16x8*)(w2b + lr * 256 + kk * 32 + lg * 8);
  }
  float b2 = sbias[t * 128 + w * 16 + lr];
  float lw = lnw[t * 128 + w * 16 + lr];
  float lb = lnb[t * 128 + w * 16 + lr];
  __syncthreads();

  f32x4 a2[4];
#pragma unroll
  for (int rt = 0; rt < 4; ++rt) { a2[rt][0] = b2; a2[rt][1] = b2; a2[rt][2] = b2; a2[rt][3] = b2; }
#pragma unroll
  for (int kk = 0; kk < 8; ++kk) {
#pragma unroll
    for (int rt = 0; rt < 4; ++rt) {
      const unsigned short* ab = (kk < 4)
          ? (lds_x + (rt * 16 + lr) * LSTR_ + kk * 32 + lg * 8)
          : ((const unsigned short*)lds_h[0] + (rt * 16 + lr) * LSTR_ + (kk - 4) * 32 + lg * 8);
      bf16x8 a = *(const bf16x8*)ab;
      a2[rt] = __builtin_amdgcn_mfma_f32_16x16x32_bf16(a, w2f[kk], a2[rt], 0, 0, 0);
    }
  }

  // LayerNorm: per-row (row = rt*16+lg*4+j) reduce over 128 cols:
  // 16-lane shuffle reduce (within lg group) then 8-wave LDS combine
#pragma unroll
  for (int rt = 0; rt < 4; ++rt)
#pragma unroll
    for (int j = 0; j < 4; ++j) {
      float v = a2[rt][j];
      float s = v, q = v * v;
#pragma unroll
      for (int m = 1; m < 16; m <<= 1) {
        s += __shfl_xor(s, m, 64);
        q += __shfl_xor(q, m, 64);
      }
      if (lr == 0) {
        int row = rt * 16 + lg * 4 + j;
        lds_ps[row * 8 + w] = s;
        lds_pq[row * 8 + w] = q;
      }
    }
  __syncthreads();
  if (tid < BM_) {
    float s = 0.f, q = 0.f;
#pragma unroll
    for (int wv = 0; wv < 8; ++wv) { s += lds_ps[tid * 8 + wv]; q += lds_pq[tid * 8 + wv]; }
    float mu = s * (1.f / 128.f);
    float var = q * (1.f / 128.f) - mu * mu;
    lds_mu[tid] = mu;
    lds_ri[tid] = rsqrtf(var + 1e-12f);
  }
  __syncthreads();
#pragma unroll
  for (int rt = 0; rt < 4; ++rt)
#pragma unroll
    for (int j = 0; j < 4; ++j) {
      int row = rt * 16 + lg * 4 + j;
      if (r0 + row < N_DST_) {
        float v = a2[rt][j];
        float y = (v - lds_mu[row]) * lds_ri[row] * lw + lb;
        float e = (y > 0.f) ? y : (__expf(y) - 1.f);
        out[(size_t)(r0 + row) * (NT_ * OUTF_) + t * OUTF_ + w * 16 + lr] = e;
      }
    }
}

extern "C" void kernel_launch(void* const* d_in, const int* in_sizes, int n_in,
                              void* d_out, int out_size, void* d_ws, size_t ws_size,
                              hipStream_t stream) {
  (void)in_sizes; (void)n_in; (void)out_size; (void)ws_size;
  const float* feature = (const float*)d_in[0];
  const int*   nidx    = (const int*)d_in[1];
  const float* W_ih    = (const float*)d_in[2];
  const float* W_hh    = (const float*)d_in[3];
  const float* b_ih    = (const float*)d_in[4];
  const float* b_hh    = (const float*)d_in[5];
  const float* fcs     = (const float*)d_in[6];
  const float* fcn     = (const float*)d_in[7];
  const float* sbias   = (const float*)d_in[8];
  const float* lnw     = (const float*)d_in[9];
  const float* lnb     = (const float*)d_in[10];
  float* out = (float*)d_out;

  // workspace layout (all 16B aligned); total ~13.8 MB
  char* ws = (char*)d_ws;
  unsigned short* feat16 = (unsigned short*)ws;                              // 12,800,000 B
  unsigned short* Wcat   = (unsigned short*)(ws + 12800000);                 //    786,432 B
  unsigned short* W2cat  = (unsigned short*)(ws + 12800000 + 786432);        //    196,608 B
  float*          bcat   = (float*)(ws + 12800000 + 786432 + 196608);        //      6,144 B

  int n4 = N_SRC_ * INF_ / 4;
  prep_feat<<<(n4 + 255) / 256, 256, 0, stream>>>(feature, feat16, n4);
  int ptot = NT_ * 512 * 256 + NT_ * 128 * 256 + NT_ * 512;
  prep_w<<<(ptot + 255) / 256, 256, 0, stream>>>(W_ih, W_hh, b_ih, b_hh, fcs, fcn, Wcat, W2cat, bcat);

  dim3 grid((N_DST_ + BM_ - 1) / BM_, NT_);
  sage_main<<<grid, 512, 0, stream>>>(feat16, nidx, Wcat, bcat, W2cat, sbias, lnw, lnb, out);
}